// Round 1
// baseline (1450.030 us; speedup 1.0000x reference)
//
#include <hip/hip_runtime.h>

// ---------------------------------------------------------------------------
// ElectrostaticFieldInteractionBlock — fp32, v2.
//   * 2 nodes/thread (32 nodes/block): halves per-thread Mf traffic,
//     doubles FMAs per Mf load.
//   * phase order B,A,C with all 9 j-outputs held in registers; single-pass
//     output write (alignment-split x4/x2/x1) -> WRITE_SIZE ~3x lower.
//   * path-4 fold: y4 = f1·a contracted per-k  (15 -> 13 virtual paths).
//   * LDS: sm[4][32][128] = 64 KB, k-index XOR-swizzled by node so the
//     4-distinct-node broadcast reads are bank-conflict-free (2 blocks/CU).
//
// Math (unchanged):
//   M_k[t,v] = (1/sqrt(128)) * sum_u Wup[t,u]*tp_w[k][u]*Wl[uoff_k+u,v]
//   j0      = K0 ( f0 P0 + IS3 sum_a f1[a] Q4[a] )        [folded per-k]
//   j1..3,c = K1 ( IS3 (f1[c] P1 + f0 Q3[c]) + sum_a g6[a][c] Q6[a] )
//   j4..8,c = K2 ( IS5 f2[c] P2 + sum_a g5[a][c] Q5[a] )
// ---------------------------------------------------------------------------

#define SWZ_OF(n) (((n) & 7) << 2)

// ------------------------- kernel 1: precompute M (fp32) --------------------
__global__ __launch_bounds__(256) void precompute_Mf(
    const float* __restrict__ Wup0, const float* __restrict__ Wup1,
    const float* __restrict__ tpw,
    const float* __restrict__ Wl0, const float* __restrict__ Wl1,
    const float* __restrict__ Wl2,
    float* __restrict__ Mf)           // Mf[m][t][v], 7*128*128 fp32
{
    __shared__ float wl[128][128];
    __shared__ float wu[32][128];
    __shared__ float tw[128];

    const int bx  = blockIdx.x;
    const int m   = bx >> 2;     // path 0..6
    const int tq  = bx & 3;      // t-quarter
    const int tid = threadIdx.x;

    const int upsel[7] = {0,0,0,1,1,1,1};
    const int wlsel[7] = {0,1,2,1,0,2,1};
    const int uoff [7] = {0,0,0,128,128,128,256};

    const float* Wup = upsel[m] ? Wup1 : Wup0;
    const float* Wl  = (wlsel[m]==0) ? Wl0 : ((wlsel[m]==1) ? Wl1 : Wl2);
    Wl += uoff[m] * 128;

    for (int idx = tid; idx < 16384; idx += 256)
        wl[idx >> 7][idx & 127] = Wl[idx];
    for (int idx = tid; idx < 4096; idx += 256)
        wu[idx >> 7][idx & 127] = Wup[(tq*32 + (idx >> 7))*128 + (idx & 127)];
    if (tid < 128) tw[tid] = tpw[m*128 + tid];
    __syncthreads();

    for (int oi = 0; oi < 16; ++oi) {
        int idx = tid + oi*256;           // 0..4095
        int tl  = idx >> 7;               // local t 0..31
        int v   = idx & 127;
        float acc = 0.f;
        #pragma unroll 4
        for (int u = 0; u < 128; ++u)
            acc += wu[tl][u] * tw[u] * wl[u][v];
        acc *= 0.08838834764831845f;      // 1/sqrt(128)
        Mf[(size_t)((m*128 + tq*32 + tl)*128 + v)] = acc;
    }
}

// ------------------------- helpers ------------------------------------------
__device__ __forceinline__ void ld8(const float* __restrict__ p, float* d) {
    float4 a = *(const float4*)p;
    float4 b = *(const float4*)(p + 4);
    d[0]=a.x; d[1]=a.y; d[2]=a.z; d[3]=a.w;
    d[4]=b.x; d[5]=b.y; d[6]=b.z; d[7]=b.w;
}

// store 9 consecutive floats at p; byte offset of p mod 16 == 4*c (c = v&3).
// Splits into aligned x4/x2/x1 stores so each (n,v)'s 36 B go out in one pass.
__device__ __forceinline__ void st9(float* __restrict__ p,
                                    const float* __restrict__ q, int c) {
    if (c == 0) {
        *(float4*)(p)     = make_float4(q[0],q[1],q[2],q[3]);
        *(float4*)(p + 4) = make_float4(q[4],q[5],q[6],q[7]);
        p[8] = q[8];
    } else if (c == 1) {
        p[0] = q[0];
        *(float2*)(p + 1) = make_float2(q[1],q[2]);
        *(float4*)(p + 3) = make_float4(q[3],q[4],q[5],q[6]);
        *(float2*)(p + 7) = make_float2(q[7],q[8]);
    } else if (c == 2) {
        *(float2*)(p)     = make_float2(q[0],q[1]);
        *(float4*)(p + 2) = make_float4(q[2],q[3],q[4],q[5]);
        *(float2*)(p + 6) = make_float2(q[6],q[7]);
        p[8] = q[8];
    } else {
        p[0] = q[0];
        *(float4*)(p + 1) = make_float4(q[1],q[2],q[3],q[4]);
        *(float4*)(p + 5) = make_float4(q[5],q[6],q[7],q[8]);
    }
}

// ------------------------- kernel 2: fused fp32 main ------------------------
__global__ __launch_bounds__(256) void fused_v2(
    const float* __restrict__ nf, const float* __restrict__ mfeat,
    const float* __restrict__ Mf, float* __restrict__ out)
{
    // [0]=s, [1..3]=v components; inner index is (k ^ SWZ_OF(n)).  64 KB.
    __shared__ float sm[4][32][128];

    const int tid = threadIdx.x;
    const int n0  = blockIdx.x * 32;

    // ---- stage node_feats: deinterleave + k-XOR-swizzle --------------------
    {
        const float4* src = (const float4*)(nf + (size_t)n0 * 512);
        for (int i = tid; i < 4096; i += 256) {
            float4 x = src[i];
            int g = i * 4;
            int n = g >> 9, c = g & 511;
            float vals[4] = {x.x, x.y, x.z, x.w};
            #pragma unroll
            for (int t = 0; t < 4; ++t) {
                int cc = c + t;
                if (cc < 128) {
                    sm[0][n][cc ^ SWZ_OF(n)] = vals[t];
                } else {
                    int d = cc - 128;               // d = 3k + comp
                    sm[1 + (d % 3)][n][(d / 3) ^ SWZ_OF(n)] = vals[t];
                }
            }
        }
    }
    __syncthreads();

    const int vt = tid & 15;            // v-column group
    const int ng = tid >> 4;            // node group 0..15
    const int v0 = vt * 8;
    const int na = ng, nb = ng + 16;    // the two nodes this thread owns
    const int sw = SWZ_OF(ng);          // (na&7)==(nb&7) -> same swizzle

    // ---- per-node multipole constants (broadcast global loads, one-time) ---
    float f0v[2], f1v[3][2], f2v[5][2];
    {
        const float* pa = mfeat + (size_t)(n0 + na) * 9;
        const float* pb = mfeat + (size_t)(n0 + nb) * 9;
        f0v[0] = pa[0]; f0v[1] = pb[0];
        #pragma unroll
        for (int c = 0; c < 3; ++c) { f1v[c][0] = pa[1+c]; f1v[c][1] = pb[1+c]; }
        #pragma unroll
        for (int c = 0; c < 5; ++c) { f2v[c][0] = pa[4+c]; f2v[c][1] = pb[4+c]; }
    }

    const float K0  = 0.04419417382415922f;   // (1/sqrt2)/16
    const float K1  = 0.029462782549439476f;  // 1/(24*sqrt2)
    const float K2  = 0.04419417382415922f;
    const float IS3 = 0.5773502691896258f;
    const float IS5 = 0.4472135954999579f;
    const float V1  = 0.31622776601683794f;   // 1/sqrt(10)
    const float W1  = 0.18257418583505536f;   // 1/sqrt(30)

    const float* M0p = Mf + 0*16384 + v0;
    const float* M1p = Mf + 1*16384 + v0;
    const float* M2p = Mf + 2*16384 + v0;
    const float* M3p = Mf + 3*16384 + v0;
    const float* M4p = Mf + 4*16384 + v0;
    const float* M5p = Mf + 5*16384 + v0;
    const float* M6p = Mf + 6*16384 + v0;

    float* outA = out + (size_t)(n0 + na) * 1152 + (size_t)v0 * 9;
    float* outB = out + (size_t)(n0 + nb) * 1152 + (size_t)v0 * 9;

    float jA[2][8];        // j0           (filled in phase A)
    float jB[2][3][8];     // j1..3        (filled in phase B)

    // =================== phase B : P1, Q3, Q6 -> j1..3 ======================
    // heaviest accumulator set (7 per (n,v)); runs first so nothing else is
    // register-resident while it is live.
    {
        float P1[2][8] = {{0}}, Q3[2][3][8] = {{{0}}}, Q6[2][3][8] = {{{0}}};
        #pragma unroll 2
        for (int k = 0; k < 128; ++k) {
            const int ix = k ^ sw;
            float sv[2] = { sm[0][na][ix], sm[0][nb][ix] };
            float a0[2] = { sm[1][na][ix], sm[1][nb][ix] };
            float a1[2] = { sm[2][na][ix], sm[2][nb][ix] };
            float a2[2] = { sm[3][na][ix], sm[3][nb][ix] };
            float m1[8], m3[8], m6[8];
            ld8(M1p + k*128, m1);
            ld8(M3p + k*128, m3);
            ld8(M6p + k*128, m6);
            #pragma unroll
            for (int j = 0; j < 8; ++j) {
                float w1 = m1[j], w3 = m3[j], w6 = m6[j];
                #pragma unroll
                for (int nn = 0; nn < 2; ++nn) {
                    P1[nn][j]    += sv[nn]*w1;
                    Q3[nn][0][j] += a0[nn]*w3;
                    Q3[nn][1][j] += a1[nn]*w3;
                    Q3[nn][2][j] += a2[nn]*w3;
                    Q6[nn][0][j] += a0[nn]*w6;
                    Q6[nn][1][j] += a1[nn]*w6;
                    Q6[nn][2][j] += a2[nn]*w6;
                }
            }
        }
        #pragma unroll
        for (int nn = 0; nn < 2; ++nn) {
            const float f0  = f0v[nn];
            const float f1a = f1v[0][nn], f1b = f1v[1][nn], f1c = f1v[2][nn];
            const float f20 = f2v[0][nn], f21 = f2v[1][nn], f22 = f2v[2][nn],
                        f23 = f2v[3][nn], f24 = f2v[4][nn];
            const float g600 = -W1*f22 - V1*f24, g601 = V1*f21,     g602 = V1*f20;
            const float g610 =  V1*f21,          g611 = 2.f*W1*f22, g612 = V1*f23;
            const float g620 =  V1*f20,          g621 = V1*f23,     g622 = -W1*f22 + V1*f24;
            #pragma unroll
            for (int j = 0; j < 8; ++j) {
                float p   = P1[nn][j];
                float q30 = Q3[nn][0][j], q31 = Q3[nn][1][j], q32 = Q3[nn][2][j];
                float q60 = Q6[nn][0][j], q61 = Q6[nn][1][j], q62 = Q6[nn][2][j];
                jB[nn][0][j] = K1*( IS3*(f1a*p + f0*q30) + g600*q60 + g610*q61 + g620*q62 );
                jB[nn][1][j] = K1*( IS3*(f1b*p + f0*q31) + g601*q60 + g611*q61 + g621*q62 );
                jB[nn][2][j] = K1*( IS3*(f1c*p + f0*q32) + g602*q60 + g612*q61 + g622*q62 );
            }
        }
    }

    // =================== phase A : folded (P0 + f1·Q4) -> j0 ================
    // j0 = sum_k [ (K0 f0 s_k) m0 + (K0 IS3 (f1·a_k)) m4 ]  — 2 virtual paths
    {
        float acc[2][8] = {{0}};
        const float c0[2] = { K0*f0v[0],       K0*f0v[1]       };
        const float cx[2] = { K0*IS3*f1v[0][0], K0*IS3*f1v[0][1] };
        const float cy[2] = { K0*IS3*f1v[1][0], K0*IS3*f1v[1][1] };
        const float cz[2] = { K0*IS3*f1v[2][0], K0*IS3*f1v[2][1] };
        #pragma unroll 2
        for (int k = 0; k < 128; ++k) {
            const int ix = k ^ sw;
            float t[2], y[2];
            #pragma unroll
            for (int nn = 0; nn < 2; ++nn) {
                const int n = (nn == 0) ? na : nb;
                t[nn] = c0[nn]*sm[0][n][ix];
                y[nn] = cx[nn]*sm[1][n][ix] + cy[nn]*sm[2][n][ix] + cz[nn]*sm[3][n][ix];
            }
            float m0[8], m4[8];
            ld8(M0p + k*128, m0);
            ld8(M4p + k*128, m4);
            #pragma unroll
            for (int j = 0; j < 8; ++j) {
                acc[0][j] += t[0]*m0[j] + y[0]*m4[j];
                acc[1][j] += t[1]*m0[j] + y[1]*m4[j];
            }
        }
        #pragma unroll
        for (int j = 0; j < 8; ++j) { jA[0][j] = acc[0][j]; jA[1][j] = acc[1][j]; }
    }

    // =================== phase C : P2, Q5 -> j4..8 + single-pass store ======
    {
        float P2[2][8] = {{0}}, Q5[2][3][8] = {{{0}}};
        #pragma unroll 2
        for (int k = 0; k < 128; ++k) {
            const int ix = k ^ sw;
            float sv[2] = { sm[0][na][ix], sm[0][nb][ix] };
            float a0[2] = { sm[1][na][ix], sm[1][nb][ix] };
            float a1[2] = { sm[2][na][ix], sm[2][nb][ix] };
            float a2[2] = { sm[3][na][ix], sm[3][nb][ix] };
            float m2[8], m5[8];
            ld8(M2p + k*128, m2);
            ld8(M5p + k*128, m5);
            #pragma unroll
            for (int j = 0; j < 8; ++j) {
                float w2 = m2[j], w5 = m5[j];
                #pragma unroll
                for (int nn = 0; nn < 2; ++nn) {
                    P2[nn][j]    += sv[nn]*w2;
                    Q5[nn][0][j] += a0[nn]*w5;
                    Q5[nn][1][j] += a1[nn]*w5;
                    Q5[nn][2][j] += a2[nn]*w5;
                }
            }
        }

        #pragma unroll
        for (int nn = 0; nn < 2; ++nn) {
            const float f1a = f1v[0][nn], f1b = f1v[1][nn], f1c = f1v[2][nn];
            const float f20 = f2v[0][nn], f21 = f2v[1][nn], f22 = f2v[2][nn],
                        f23 = f2v[3][nn], f24 = f2v[4][nn];
            float* ob = (nn == 0) ? outA : outB;
            #pragma unroll
            for (int vv = 0; vv < 8; ++vv) {
                float p   = P2[nn][vv];
                float q50 = Q5[nn][0][vv], q51 = Q5[nn][1][vv], q52 = Q5[nn][2][vv];
                float q[9];
                q[0] = jA[nn][vv];
                q[1] = jB[nn][0][vv];
                q[2] = jB[nn][1][vv];
                q[3] = jB[nn][2][vv];
                q[4] = K2*( IS5*f20*p + V1*f1c*q50                   + V1*f1a*q52 );
                q[5] = K2*( IS5*f21*p + V1*f1b*q50 + V1*f1a*q51 );
                q[6] = K2*( IS5*f22*p - W1*f1a*q50 + 2.f*W1*f1b*q51 - W1*f1c*q52 );
                q[7] = K2*( IS5*f23*p              + V1*f1c*q51     + V1*f1b*q52 );
                q[8] = K2*( IS5*f24*p - V1*f1a*q50                   + V1*f1c*q52 );
                st9(ob + vv*9, q, vv & 3);
            }
        }
    }
}

// ------------------------------ launcher ------------------------------------
extern "C" void kernel_launch(void* const* d_in, const int* in_sizes, int n_in,
                              void* d_out, int out_size, void* d_ws, size_t ws_size,
                              hipStream_t stream) {
    const float* nf   = (const float*)d_in[0];
    const float* mf   = (const float*)d_in[1];
    const float* Wup0 = (const float*)d_in[2];
    const float* Wup1 = (const float*)d_in[3];
    const float* tpw  = (const float*)d_in[4];
    const float* Wl0  = (const float*)d_in[5];
    const float* Wl1  = (const float*)d_in[6];
    const float* Wl2  = (const float*)d_in[7];
    float* out = (float*)d_out;
    float* Mf  = (float*)d_ws;                 // 7*128*128 fp32 = 458,752 B

    const int N = in_sizes[0] / 512;           // 65536 nodes
    precompute_Mf<<<28, 256, 0, stream>>>(Wup0, Wup1, tpw, Wl0, Wl1, Wl2, Mf);
    fused_v2<<<N / 32, 256, 0, stream>>>(nf, mf, Mf, out);
}

// Round 2
// 761.912 us; speedup vs baseline: 1.9031x; 1.9031x over previous
//
#include <hip/hip_runtime.h>

// ---------------------------------------------------------------------------
// ElectrostaticFieldInteractionBlock — v3: MFMA fp16 2-term split.
//
//   All 15 products P_k = s·M_k / Q_ka = v_a·M_k are 16x16x32 f16 MFMAs.
//   Precision: M stored as fp16 hi+lo (M = Mh + Ml), node feats rounded to
//   fp16 once:  x·M ≈ xh·Mh + xh·Ml  (error = A-side rounding only, ~1e-3
//   max vs 1.56e-2 tolerance).  Accumulation in fp32 (MFMA C-regs).
//
//   Block = 64 nodes × 128 v, 4 independent waves (16 nodes each), no
//   barriers in the main loop.  A-frags live in 64 VGPRs for the whole
//   kernel.  M^T stored [path][v][k] fp16 so B-frags are 16 B loads
//   (448 KB total, L2-resident).  Outputs staged per-wave in LDS, flushed
//   as 64B-aligned float4 streams (single-pass writes).
//
//   Workspace: Bh (229,376 B) + Bl (229,376 B) = 458,752 B (same as before).
// ---------------------------------------------------------------------------

typedef _Float16 f16;
typedef f16   f16x8 __attribute__((ext_vector_type(8)));
typedef float f32x4 __attribute__((ext_vector_type(4)));

#define MFMA16(a,b,c) __builtin_amdgcn_mfma_f32_16x16x32_f16((a),(b),(c),0,0,0)

// ------------------------- kernel 1: precompute M (fp16 hi/lo, transposed) --
__global__ __launch_bounds__(256) void precompute_M16(
    const float* __restrict__ Wup0, const float* __restrict__ Wup1,
    const float* __restrict__ tpw,
    const float* __restrict__ Wl0, const float* __restrict__ Wl1,
    const float* __restrict__ Wl2,
    f16* __restrict__ Bh, f16* __restrict__ Bl)   // [path][v][k], 7*128*128
{
    __shared__ float wl[128][128];
    __shared__ float wu[32][128];
    __shared__ float tw[128];

    const int bx  = blockIdx.x;
    const int m   = bx >> 2;     // path 0..6
    const int tq  = bx & 3;      // k-quarter
    const int tid = threadIdx.x;

    const int upsel[7] = {0,0,0,1,1,1,1};
    const int wlsel[7] = {0,1,2,1,0,2,1};
    const int uoff [7] = {0,0,0,128,128,128,256};

    const float* Wup = upsel[m] ? Wup1 : Wup0;
    const float* Wl  = (wlsel[m]==0) ? Wl0 : ((wlsel[m]==1) ? Wl1 : Wl2);
    Wl += uoff[m] * 128;

    for (int idx = tid; idx < 16384; idx += 256)
        wl[idx >> 7][idx & 127] = Wl[idx];
    for (int idx = tid; idx < 4096; idx += 256)
        wu[idx >> 7][idx & 127] = Wup[(tq*32 + (idx >> 7))*128 + (idx & 127)];
    if (tid < 128) tw[tid] = tpw[m*128 + tid];
    __syncthreads();

    for (int oi = 0; oi < 16; ++oi) {
        int idx = tid + oi*256;           // 0..4095
        int tl  = idx >> 7;               // local k 0..31
        int v   = idx & 127;
        float acc = 0.f;
        #pragma unroll 4
        for (int u = 0; u < 128; ++u)
            acc += wu[tl][u] * tw[u] * wl[u][v];
        acc *= 0.08838834764831845f;      // 1/sqrt(128)
        f16 h = (f16)acc;
        f16 l = (f16)(acc - (float)h);
        size_t o = ((size_t)(m*128 + v))*128 + (size_t)(tq*32 + tl); // [m][v][k]
        Bh[o] = h;
        Bl[o] = l;
    }
}

// ------------------------- kernel 2: MFMA main ------------------------------
__global__ __launch_bounds__(256) void fused_mfma(
    const float* __restrict__ nf, const float* __restrict__ mfeat,
    const f16* __restrict__ Bh, const f16* __restrict__ Bl,
    float* __restrict__ out)
{
    __shared__ float mfl[576];           // 64 nodes × 9 coeffs     (2.3 KB)
    __shared__ float ostg[4][2304];      // per-wave 16n×16v×9 f32  (36.9 KB)

    const int tid  = threadIdx.x;
    const int w    = tid >> 6;           // wave 0..3
    const int lane = tid & 63;
    const int n0   = blockIdx.x * 64;

    // ---- stage mfeat for the block's 64 nodes ------------------------------
    if (tid < 144)
        ((float4*)mfl)[tid] = ((const float4*)(mfeat + (size_t)n0 * 9))[tid];

    // ---- load + convert this lane's A-fragments (held in regs all kernel) --
    const int mrow = lane & 15;          // node within wave's 16
    const int kg   = lane >> 4;          // k-group 0..3
    const int node = n0 + w*16 + mrow;
    const float* nfp = nf + (size_t)node * 512;

    f16x8 As[4], Av0[4], Av1[4], Av2[4];   // [kstep]
    #pragma unroll
    for (int t = 0; t < 4; ++t) {
        const int k0 = t*32 + kg*8;
        float4 sA = *(const float4*)(nfp + k0);
        float4 sB = *(const float4*)(nfp + k0 + 4);
        f16x8 a;
        a[0]=(f16)sA.x; a[1]=(f16)sA.y; a[2]=(f16)sA.z; a[3]=(f16)sA.w;
        a[4]=(f16)sB.x; a[5]=(f16)sB.y; a[6]=(f16)sB.z; a[7]=(f16)sB.w;
        As[t] = a;
        const float* vp = nfp + 128 + 3*k0;     // 24 floats, 16B aligned
        float vv[24];
        #pragma unroll
        for (int q = 0; q < 6; ++q) {
            float4 x = *(const float4*)(vp + q*4);
            vv[q*4+0]=x.x; vv[q*4+1]=x.y; vv[q*4+2]=x.z; vv[q*4+3]=x.w;
        }
        f16x8 a0, a1, a2;
        #pragma unroll
        for (int e = 0; e < 8; ++e) {
            a0[e]=(f16)vv[3*e+0]; a1[e]=(f16)vv[3*e+1]; a2[e]=(f16)vv[3*e+2];
        }
        Av0[t]=a0; Av1[t]=a1; Av2[t]=a2;
    }
    __syncthreads();   // mfl ready — only block-wide barrier in the kernel

    // ---- B-frag lane base: B[path][v = nt*16 + (lane&15)][k = t*32 + kg*8] -
    const int boff = (lane & 15)*128 + kg*8;
    const f16* b0h = Bh + 0*16384 + boff;  const f16* b0l = Bl + 0*16384 + boff;
    const f16* b1h = Bh + 1*16384 + boff;  const f16* b1l = Bl + 1*16384 + boff;
    const f16* b2h = Bh + 2*16384 + boff;  const f16* b2l = Bl + 2*16384 + boff;
    const f16* b3h = Bh + 3*16384 + boff;  const f16* b3l = Bl + 3*16384 + boff;
    const f16* b4h = Bh + 4*16384 + boff;  const f16* b4l = Bl + 4*16384 + boff;
    const f16* b5h = Bh + 5*16384 + boff;  const f16* b5l = Bl + 5*16384 + boff;
    const f16* b6h = Bh + 6*16384 + boff;  const f16* b6l = Bl + 6*16384 + boff;

    const float K0  = 0.04419417382415922f;   // (1/sqrt2)/16
    const float K1  = 0.029462782549439476f;  // 1/(24*sqrt2)
    const float K2  = 0.04419417382415922f;
    const float IS3 = 0.5773502691896258f;
    const float IS5 = 0.4472135954999579f;
    const float V1  = 0.31622776601683794f;   // 1/sqrt(10)
    const float W1  = 0.18257418583505536f;   // 1/sqrt(30)

    for (int nt = 0; nt < 8; ++nt) {
        const int nb = nt*2048;

        // ============ phase B : P1, Q3, Q6 -> j1..3 ========================
        {
            f32x4 P1={0,0,0,0}, Q30={0,0,0,0}, Q31={0,0,0,0}, Q32={0,0,0,0},
                  Q60={0,0,0,0}, Q61={0,0,0,0}, Q62={0,0,0,0};
            #pragma unroll
            for (int t = 0; t < 4; ++t) {
                const int o = nb + t*32;
                f16x8 m1h = *(const f16x8*)(b1h + o);
                f16x8 m1l = *(const f16x8*)(b1l + o);
                f16x8 m3h = *(const f16x8*)(b3h + o);
                f16x8 m3l = *(const f16x8*)(b3l + o);
                f16x8 m6h = *(const f16x8*)(b6h + o);
                f16x8 m6l = *(const f16x8*)(b6l + o);
                P1  = MFMA16(As[t],  m1h, P1);   P1  = MFMA16(As[t],  m1l, P1);
                Q30 = MFMA16(Av0[t], m3h, Q30);  Q30 = MFMA16(Av0[t], m3l, Q30);
                Q31 = MFMA16(Av1[t], m3h, Q31);  Q31 = MFMA16(Av1[t], m3l, Q31);
                Q32 = MFMA16(Av2[t], m3h, Q32);  Q32 = MFMA16(Av2[t], m3l, Q32);
                Q60 = MFMA16(Av0[t], m6h, Q60);  Q60 = MFMA16(Av0[t], m6l, Q60);
                Q61 = MFMA16(Av1[t], m6h, Q61);  Q61 = MFMA16(Av1[t], m6l, Q61);
                Q62 = MFMA16(Av2[t], m6h, Q62);  Q62 = MFMA16(Av2[t], m6l, Q62);
            }
            #pragma unroll
            for (int r = 0; r < 4; ++r) {
                const int nl = kg*4 + r;                 // D row -> node
                const float* fp = &mfl[(w*16 + nl)*9];
                float f0=fp[0], f1a=fp[1], f1b=fp[2], f1c=fp[3];
                float f20=fp[4], f21=fp[5], f22=fp[6], f23=fp[7], f24=fp[8];
                float g600 = -W1*f22 - V1*f24, g601 = V1*f21,     g602 = V1*f20;
                float g610 =  V1*f21,          g611 = 2.f*W1*f22, g612 = V1*f23;
                float g620 =  V1*f20,          g621 = V1*f23,     g622 = -W1*f22 + V1*f24;
                float p = P1[r];
                float q30=Q30[r], q31=Q31[r], q32=Q32[r];
                float q60=Q60[r], q61=Q61[r], q62=Q62[r];
                float* og = &ostg[w][nl*144 + (lane & 15)*9];
                og[1] = K1*( IS3*(f1a*p + f0*q30) + g600*q60 + g610*q61 + g620*q62 );
                og[2] = K1*( IS3*(f1b*p + f0*q31) + g601*q60 + g611*q61 + g621*q62 );
                og[3] = K1*( IS3*(f1c*p + f0*q32) + g602*q60 + g612*q61 + g622*q62 );
            }
        }

        // ============ phase A : P0, Q4 -> j0 ===============================
        {
            f32x4 P0={0,0,0,0}, Q40={0,0,0,0}, Q41={0,0,0,0}, Q42={0,0,0,0};
            #pragma unroll
            for (int t = 0; t < 4; ++t) {
                const int o = nb + t*32;
                f16x8 m0h = *(const f16x8*)(b0h + o);
                f16x8 m0l = *(const f16x8*)(b0l + o);
                f16x8 m4h = *(const f16x8*)(b4h + o);
                f16x8 m4l = *(const f16x8*)(b4l + o);
                P0  = MFMA16(As[t],  m0h, P0);   P0  = MFMA16(As[t],  m0l, P0);
                Q40 = MFMA16(Av0[t], m4h, Q40);  Q40 = MFMA16(Av0[t], m4l, Q40);
                Q41 = MFMA16(Av1[t], m4h, Q41);  Q41 = MFMA16(Av1[t], m4l, Q41);
                Q42 = MFMA16(Av2[t], m4h, Q42);  Q42 = MFMA16(Av2[t], m4l, Q42);
            }
            #pragma unroll
            for (int r = 0; r < 4; ++r) {
                const int nl = kg*4 + r;
                const float* fp = &mfl[(w*16 + nl)*9];
                float f0=fp[0], f1a=fp[1], f1b=fp[2], f1c=fp[3];
                float* og = &ostg[w][nl*144 + (lane & 15)*9];
                og[0] = K0*( f0*P0[r] + IS3*(f1a*Q40[r] + f1b*Q41[r] + f1c*Q42[r]) );
            }
        }

        // ============ phase C : P2, Q5 -> j4..8 ============================
        {
            f32x4 P2={0,0,0,0}, Q50={0,0,0,0}, Q51={0,0,0,0}, Q52={0,0,0,0};
            #pragma unroll
            for (int t = 0; t < 4; ++t) {
                const int o = nb + t*32;
                f16x8 m2h = *(const f16x8*)(b2h + o);
                f16x8 m2l = *(const f16x8*)(b2l + o);
                f16x8 m5h = *(const f16x8*)(b5h + o);
                f16x8 m5l = *(const f16x8*)(b5l + o);
                P2  = MFMA16(As[t],  m2h, P2);   P2  = MFMA16(As[t],  m2l, P2);
                Q50 = MFMA16(Av0[t], m5h, Q50);  Q50 = MFMA16(Av0[t], m5l, Q50);
                Q51 = MFMA16(Av1[t], m5h, Q51);  Q51 = MFMA16(Av1[t], m5l, Q51);
                Q52 = MFMA16(Av2[t], m5h, Q52);  Q52 = MFMA16(Av2[t], m5l, Q52);
            }
            #pragma unroll
            for (int r = 0; r < 4; ++r) {
                const int nl = kg*4 + r;
                const float* fp = &mfl[(w*16 + nl)*9];
                float f1a=fp[1], f1b=fp[2], f1c=fp[3];
                float f20=fp[4], f21=fp[5], f22=fp[6], f23=fp[7], f24=fp[8];
                float p = P2[r];
                float q50=Q50[r], q51=Q51[r], q52=Q52[r];
                float* og = &ostg[w][nl*144 + (lane & 15)*9];
                og[4] = K2*( IS5*f20*p + V1*f1c*q50                    + V1*f1a*q52 );
                og[5] = K2*( IS5*f21*p + V1*f1b*q50 + V1*f1a*q51 );
                og[6] = K2*( IS5*f22*p - W1*f1a*q50 + 2.f*W1*f1b*q51  - W1*f1c*q52 );
                og[7] = K2*( IS5*f23*p              + V1*f1c*q51      + V1*f1b*q52 );
                og[8] = K2*( IS5*f24*p - V1*f1a*q50                    + V1*f1c*q52 );
            }
        }

        // ============ flush this n-tile: coalesced 64B-aligned stores ======
        // wave-local data (written and read by the same wave; lockstep order)
        #pragma unroll
        for (int i = 0; i < 9; ++i) {
            int idx = lane + i*64;               // 0..575
            int nl  = idx / 36;                  // node 0..15
            int q   = idx - nl*36;               // float4 index 0..35
            float4 val = *(const float4*)&ostg[w][nl*144 + q*4];
            *(float4*)(out + (size_t)(n0 + w*16 + nl)*1152 + nt*144 + q*4) = val;
        }
    }
}

// ------------------------------ launcher ------------------------------------
extern "C" void kernel_launch(void* const* d_in, const int* in_sizes, int n_in,
                              void* d_out, int out_size, void* d_ws, size_t ws_size,
                              hipStream_t stream) {
    const float* nf   = (const float*)d_in[0];
    const float* mf   = (const float*)d_in[1];
    const float* Wup0 = (const float*)d_in[2];
    const float* Wup1 = (const float*)d_in[3];
    const float* tpw  = (const float*)d_in[4];
    const float* Wl0  = (const float*)d_in[5];
    const float* Wl1  = (const float*)d_in[6];
    const float* Wl2  = (const float*)d_in[7];
    float* out = (float*)d_out;

    f16* Bh = (f16*)d_ws;                      // 7*128*128 fp16 = 229,376 B
    f16* Bl = Bh + 7*128*128;                  // + 229,376 B = 458,752 total

    const int N = in_sizes[0] / 512;           // 65536 nodes
    precompute_M16<<<28, 256, 0, stream>>>(Wup0, Wup1, tpw, Wl0, Wl1, Wl2, Bh, Bl);
    fused_mfma<<<N / 64, 256, 0, stream>>>(nf, mf, Bh, Bl, out);
}